// Round 2
// baseline (4081.724 us; speedup 1.0000x reference)
//
#include <hip/hip_runtime.h>
#include <hip/hip_bf16.h>
#include <math.h>

#define L_LAYERS 4
#define BIMG 8
#define PATCH_H 37
#define PATCH_W 37
#define PP 1369
#define DD 1024
#define JJ 768
#define HOUT 518
#define WOUT 518
#define PPAD 1408   // 22 * 64
#define NPAIR 28

typedef __bf16 bf16x8 __attribute__((ext_vector_type(8)));
typedef float floatx4 __attribute__((ext_vector_type(4)));

__device__ __forceinline__ unsigned short f2bf(float f) {
  unsigned int u = __float_as_uint(f);
  u = u + 0x7fffu + ((u >> 16) & 1u);   // round-to-nearest-even
  return (unsigned short)(u >> 16);
}

// ---------------------------------------------------------------------------
// K1: per-(l,b) mean of features (float32).  grid (43, 32), block 256.
__global__ __launch_bounds__(256) void k1_mu(const float* __restrict__ x,
                                             float* __restrict__ mu_acc) {
  const int lb = blockIdx.y;
  const float* base = x + (size_t)lb * PP * DD;
  const int N4 = PP * DD / 4;   // 350464
  float s = 0.0f;
  for (int idx = blockIdx.x * 256 + threadIdx.x; idx < N4; idx += gridDim.x * 256) {
    float4 u = *(const float4*)(base + (size_t)idx * 4);
    s += u.x + u.y + u.z + u.w;
  }
  for (int off = 1; off < 64; off <<= 1) s += __shfl_xor(s, off, 64);
  __shared__ float red[4];
  if ((threadIdx.x & 63) == 0) red[threadIdx.x >> 6] = s;
  __syncthreads();
  if (threadIdx.x == 0)
    atomicAdd(&mu_acc[lb], red[0] + red[1] + red[2] + red[3]);
}

// ---------------------------------------------------------------------------
// K2: box-sum pool (window r, zero pad) + subtract cnt*mu + L2 normalize ->
// bf16 rf. Scale factors rsqrt(var) and 1/r^2 cancel under normalization.
// grid (PPAD, 32), block 256 (4 d-elements per thread). Rows >= PP -> zeros.
__global__ __launch_bounds__(256) void k2_pool(const float* __restrict__ x,
                                               const float* __restrict__ mu_acc,
                                               unsigned short* __restrict__ rf,
                                               int r) {
  const int p  = blockIdx.x;   // padded patch index
  const int lb = blockIdx.y;
  const int tid = threadIdx.x;
  const int d0 = tid * 4;
  const size_t outbase = ((size_t)lb * PPAD + p) * DD;
  if (p >= PP) {
    ushort4 z; z.x = 0; z.y = 0; z.z = 0; z.w = 0;
    *(ushort4*)(rf + outbase + d0) = z;
    return;
  }
  const float mu = mu_acc[lb] * (1.0f / ((float)PP * (float)DD));
  const int ph = p / PATCH_W, pw = p % PATCH_W;
  const int pad = r >> 1;
  float s0 = 0, s1 = 0, s2 = 0, s3 = 0;
  int cnt = 0;
  for (int dy = -pad; dy <= pad; dy++) {
    int qh = ph + dy; if (qh < 0 || qh >= PATCH_H) continue;
    for (int dx = -pad; dx <= pad; dx++) {
      int qw = pw + dx; if (qw < 0 || qw >= PATCH_W) continue;
      cnt++;
      const float* src = x + ((size_t)lb * PP + qh * PATCH_W + qw) * DD + d0;
      float4 u = *(const float4*)src;
      s0 += u.x; s1 += u.y; s2 += u.z; s3 += u.w;
    }
  }
  const float cm = (float)cnt * mu;
  s0 -= cm; s1 -= cm; s2 -= cm; s3 -= cm;
  float sq = s0 * s0 + s1 * s1 + s2 * s2 + s3 * s3;
  for (int off = 1; off < 64; off <<= 1) sq += __shfl_xor(sq, off, 64);
  __shared__ float red[4];
  if ((tid & 63) == 0) red[tid >> 6] = sq;
  __syncthreads();
  const float tot = red[0] + red[1] + red[2] + red[3];
  const float rn = rsqrtf(tot);
  ushort4 o;
  o.x = f2bf(s0 * rn); o.y = f2bf(s1 * rn); o.z = f2bf(s2 * rn); o.w = f2bf(s3 * rn);
  *(ushort4*)(rf + outbase + d0) = o;
}

// ---------------------------------------------------------------------------
// K3: per (l, unordered pair i<j): C = rf_i @ rf_j^T (1369x1369, K=1024) via
// bf16 MFMA 16x16x32, 64x64 block tile. Fused epilogue: row-max -> mind[l,i,j,p],
// col-max -> mind[l,j,i,q], via atomicMax on uint encoding of (dot + 2.0).
// grid (22, 22, L_LAYERS*NPAIR), block 256 (4 waves).
__global__ __launch_bounds__(256) void k3_pairdots(const unsigned short* __restrict__ rf,
                                                   unsigned int* __restrict__ mind) {
  const int l = blockIdx.z / NPAIR;
  int rem = blockIdx.z % NPAIR;
  int i = 0, span = BIMG - 1;
  while (rem >= span) { rem -= span; span--; i++; }
  const int j = i + 1 + rem;

  const int rowbase = blockIdx.x * 64;
  const int colbase = blockIdx.y * 64;
  const unsigned short* A  = rf + ((size_t)(l * BIMG + i) * PPAD + rowbase) * DD;
  const unsigned short* Bp = rf + ((size_t)(l * BIMG + j) * PPAD + colbase) * DD;

  // LDS: 64 rows x 32 k, row stride 40 bf16 (80 B -> 16B aligned frags, ~2-way banks)
  __shared__ __align__(16) unsigned short lA[64 * 40];
  __shared__ __align__(16) unsigned short lB[64 * 40];

  const int tid  = threadIdx.x;
  const int lane = tid & 63;
  const int wave = tid >> 6;
  const int lrow = lane & 15;
  const int quad = lane >> 4;

  floatx4 acc[4];
#pragma unroll
  for (int c = 0; c < 4; c++) acc[c] = (floatx4){0.f, 0.f, 0.f, 0.f};

  const int srow   = tid >> 2;        // 0..63
  const int schunk = (tid & 3) * 8;   // 0,8,16,24

  for (int k0 = 0; k0 < DD; k0 += 32) {
    float4 va = *(const float4*)(A  + (size_t)srow * DD + k0 + schunk);
    float4 vb = *(const float4*)(Bp + (size_t)srow * DD + k0 + schunk);
    __syncthreads();   // previous iter's fragment reads done before overwrite
    *(float4*)(lA + srow * 40 + schunk) = va;
    *(float4*)(lB + srow * 40 + schunk) = vb;
    __syncthreads();
    const bf16x8 af = *(const bf16x8*)(lA + (wave * 16 + lrow) * 40 + quad * 8);
#pragma unroll
    for (int ct = 0; ct < 4; ct++) {
      const bf16x8 bfv = *(const bf16x8*)(lB + (ct * 16 + lrow) * 40 + quad * 8);
      acc[ct] = __builtin_amdgcn_mfma_f32_16x16x32_bf16(af, bfv, acc[ct], 0, 0, 0);
    }
  }

  unsigned int* mrow = mind + ((size_t)(l * BIMG + i) * BIMG + j) * PP;
  unsigned int* mcol = mind + ((size_t)(l * BIMG + j) * BIMG + i) * PP;

  // row-max over the 64 cols of this block (cols >= PP masked)
#pragma unroll
  for (int reg = 0; reg < 4; reg++) {
    const int gr = rowbase + wave * 16 + quad * 4 + reg;
    float v = -1e30f;
#pragma unroll
    for (int ct = 0; ct < 4; ct++) {
      const int gc = colbase + ct * 16 + lrow;
      if (gc < PP) v = fmaxf(v, acc[ct][reg]);
    }
    for (int off = 1; off < 16; off <<= 1) v = fmaxf(v, __shfl_xor(v, off, 64));
    if (lrow == 0 && gr < PP)
      atomicMax(mrow + gr, __float_as_uint(v + 2.0f));   // dot+2 in [1,3] > 0
  }
  // col-max over this block's 64 rows (rows >= PP masked)
#pragma unroll
  for (int ct = 0; ct < 4; ct++) {
    const int gc = colbase + ct * 16 + lrow;
    float v = -1e30f;
#pragma unroll
    for (int reg = 0; reg < 4; reg++) {
      const int gr = rowbase + wave * 16 + quad * 4 + reg;
      if (gr < PP) v = fmaxf(v, acc[ct][reg]);
    }
    for (int off = 16; off < 64; off <<= 1) v = fmaxf(v, __shfl_xor(v, off, 64));
    if (quad == 0 && gc < PP && v > -1e29f)
      atomicMax(mcol + gc, __float_as_uint(v + 2.0f));
  }
}

// ---------------------------------------------------------------------------
// K4: per (i,p): for each l, dist=sqrt(2-2*maxdot) over b!=i, mean of 2 smallest;
// accumulate (1/(L*3)) * sum_l into scores.
__global__ void k4_scores(const unsigned int* __restrict__ mind,
                          float* __restrict__ scores) {
  const int idx = blockIdx.x * 256 + threadIdx.x;
  if (idx >= BIMG * PP) return;
  const int i = idx / PP, p = idx % PP;
  float accum = 0.0f;
  for (int l = 0; l < L_LAYERS; l++) {
    float m1 = 1e30f, m2 = 1e30f;
    for (int b = 0; b < BIMG; b++) {
      if (b == i) continue;
      const unsigned int enc = mind[((size_t)(l * BIMG + i) * BIMG + b) * PP + p];
      const float dot = __uint_as_float(enc) - 2.0f;
      const float d2 = fmaxf(2.0f - 2.0f * dot, 1e-12f);
      const float dist = sqrtf(d2);
      if (dist < m1) { m2 = m1; m1 = dist; }
      else if (dist < m2) { m2 = dist; }
    }
    accum += 0.5f * (m1 + m2);
  }
  scores[idx] += accum * (1.0f / (float)(L_LAYERS * 3));
}

// ---------------------------------------------------------------------------
// K5: img_scores[i] = max_p scores[i,p].  grid 8, block 256.
__global__ void k5_imgmax(const float* __restrict__ scores, float* __restrict__ img) {
  const int i = blockIdx.x;
  float m = -1e30f;
  for (int p = threadIdx.x; p < PP; p += 256) m = fmaxf(m, scores[i * PP + p]);
  for (int off = 1; off < 64; off <<= 1) m = fmaxf(m, __shfl_xor(m, off, 64));
  __shared__ float red[4];
  if ((threadIdx.x & 63) == 0) red[threadIdx.x >> 6] = m;
  __syncthreads();
  if (threadIdx.x == 0)
    img[i] = fmaxf(fmaxf(red[0], red[1]), fmaxf(red[2], red[3]));
}

// ---------------------------------------------------------------------------
// K6: cls normalize -> sim (8x8) -> RsCIN for k=1,2,3 -> mean -> out[0:8].
// one block, 64 threads.  cls is float32.
__global__ void k6_final(const float* __restrict__ cls,
                         const float* __restrict__ img,
                         float* __restrict__ out) {
  __shared__ float norms[BIMG];
  __shared__ float sim[BIMG][BIMG];
  const int t = threadIdx.x;
  if (t < BIMG) {
    float s = 0;
    for (int d = 0; d < JJ; d++) { float v = cls[t * JJ + d]; s += v * v; }
    norms[t] = sqrtf(s);
  }
  __syncthreads();
  {
    const int ii = t >> 3, jj = t & 7;
    float s = 0;
    for (int d = 0; d < JJ; d++) s += cls[ii * JJ + d] * cls[jj * JJ + d];
    sim[ii][jj] = s / (norms[ii] * norms[jj]);
  }
  __syncthreads();
  if (t < BIMG) {
    float v[8]; int id[8];
    for (int a = 0; a < 8; a++) { v[a] = sim[t][a]; id[a] = a; }
    for (int a = 0; a < 8; a++) {            // stable selection sort, descending
      int best = a;
      for (int b = a + 1; b < 8; b++) if (v[b] > v[best]) best = b;
      float tv = v[a]; v[a] = v[best]; v[best] = tv;
      int ti = id[a]; id[a] = id[best]; id[best] = ti;
    }
    float res = 0;
    for (int k = 1; k <= 3; k++) {
      float num = 0, den = 0;
      for (int a = 0; a < k; a++) { num += v[a] * img[id[a]]; den += v[a]; }
      res += num / den;
    }
    out[t] = res * (1.0f / 3.0f);
  }
}

// ---------------------------------------------------------------------------
// K7: bilinear upsample scores (8,37,37) -> pixel (8,518,518) -> out[8:].
__global__ void k7_pixel(const float* __restrict__ scores,
                         float* __restrict__ out) {
  const int idx = blockIdx.x * 256 + threadIdx.x;
  if (idx >= BIMG * HOUT * WOUT) return;
  const int b = idx / (HOUT * WOUT);
  const int rem = idx % (HOUT * WOUT);
  const int Y = rem / WOUT, X = rem % WOUT;
  const float sy = (float)(PATCH_H - 1) / (float)(HOUT - 1);
  const float sx = (float)(PATCH_W - 1) / (float)(WOUT - 1);
  float py = (float)Y * sy;
  float px = (float)X * sx;
  int y0 = (int)floorf(py); y0 = min(max(y0, 0), PATCH_H - 1);
  int x0 = (int)floorf(px); x0 = min(max(x0, 0), PATCH_W - 1);
  const int y1 = min(y0 + 1, PATCH_H - 1);
  const int x1 = min(x0 + 1, PATCH_W - 1);
  const float wy = py - (float)y0, wx = px - (float)x0;
  const float* sc = scores + (size_t)b * PP;
  const float v =
      (1.f - wy) * ((1.f - wx) * sc[y0 * PATCH_W + x0] + wx * sc[y0 * PATCH_W + x1]) +
      wy         * ((1.f - wx) * sc[y1 * PATCH_W + x0] + wx * sc[y1 * PATCH_W + x1]);
  out[8 + idx] = v;
}

// ---------------------------------------------------------------------------
extern "C" void kernel_launch(void* const* d_in, const int* in_sizes, int n_in,
                              void* d_out, int out_size, void* d_ws, size_t ws_size,
                              hipStream_t stream) {
  const float* feat = (const float*)d_in[0];  // (4,8,1369,1024) f32
  const float* cls  = (const float*)d_in[1];  // (8,768) f32
  float* out = (float*)d_out;

  char* ws = (char*)d_ws;
  size_t off = 0;
  unsigned short* rf = (unsigned short*)(ws + off);
  off += (size_t)L_LAYERS * BIMG * PPAD * DD * 2;               // 92,274,688
  unsigned int* mind = (unsigned int*)(ws + off);
  off += (size_t)L_LAYERS * BIMG * BIMG * PP * 4;               // 1,401,856
  float* scores = (float*)(ws + off);
  off += (size_t)BIMG * PP * 4;
  float* mu_acc = (float*)(ws + off);
  off += 32 * 4;
  float* img = (float*)(ws + off);
  off += 8 * 4;

  hipMemsetAsync(mu_acc, 0, 32 * 4, stream);
  hipMemsetAsync(scores, 0, (size_t)BIMG * PP * 4, stream);
  k1_mu<<<dim3(43, 32), 256, 0, stream>>>(feat, mu_acc);

  const int rlist[3] = {1, 3, 5};
  for (int ri = 0; ri < 3; ri++) {
    k2_pool<<<dim3(PPAD, 32), 256, 0, stream>>>(feat, mu_acc, rf, rlist[ri]);
    hipMemsetAsync(mind, 0, (size_t)L_LAYERS * BIMG * BIMG * PP * 4, stream);
    k3_pairdots<<<dim3(22, 22, L_LAYERS * NPAIR), 256, 0, stream>>>(rf, mind);
    k4_scores<<<(BIMG * PP + 255) / 256, 256, 0, stream>>>(mind, scores);
  }
  k5_imgmax<<<8, 256, 0, stream>>>(scores, img);
  k6_final<<<1, 64, 0, stream>>>(cls, img, out);
  k7_pixel<<<(BIMG * HOUT * WOUT + 255) / 256, 256, 0, stream>>>(scores, out);
}

// Round 3
// 2926.730 us; speedup vs baseline: 1.3946x; 1.3946x over previous
//
#include <hip/hip_runtime.h>
#include <hip/hip_bf16.h>
#include <math.h>

#define L_LAYERS 4
#define BIMG 8
#define PATCH_H 37
#define PATCH_W 37
#define PP 1369
#define DD 1024
#define JJ 768
#define HOUT 518
#define WOUT 518
#define PPAD 1408   // 11 * 128
#define NPAIR 28

typedef __bf16 bf16x8 __attribute__((ext_vector_type(8)));
typedef float floatx4 __attribute__((ext_vector_type(4)));

__device__ __forceinline__ unsigned short f2bf(float f) {
  unsigned int u = __float_as_uint(f);
  u = u + 0x7fffu + ((u >> 16) & 1u);   // round-to-nearest-even
  return (unsigned short)(u >> 16);
}

// async global->LDS, 16B per lane; LDS dest = wave-uniform base + lane*16
__device__ __forceinline__ void gload_lds16(const unsigned short* gptr,
                                            unsigned short* lptr) {
  __builtin_amdgcn_global_load_lds(
      (const __attribute__((address_space(1))) unsigned int*)gptr,
      (__attribute__((address_space(3))) unsigned int*)lptr, 16, 0, 0);
}

// ---------------------------------------------------------------------------
// K1: per-(l,b) mean of features (float32).  grid (43, 32), block 256.
__global__ __launch_bounds__(256) void k1_mu(const float* __restrict__ x,
                                             float* __restrict__ mu_acc) {
  const int lb = blockIdx.y;
  const float* base = x + (size_t)lb * PP * DD;
  const int N4 = PP * DD / 4;   // 350464
  float s = 0.0f;
  for (int idx = blockIdx.x * 256 + threadIdx.x; idx < N4; idx += gridDim.x * 256) {
    float4 u = *(const float4*)(base + (size_t)idx * 4);
    s += u.x + u.y + u.z + u.w;
  }
  for (int off = 1; off < 64; off <<= 1) s += __shfl_xor(s, off, 64);
  __shared__ float red[4];
  if ((threadIdx.x & 63) == 0) red[threadIdx.x >> 6] = s;
  __syncthreads();
  if (threadIdx.x == 0)
    atomicAdd(&mu_acc[lb], red[0] + red[1] + red[2] + red[3]);
}

// ---------------------------------------------------------------------------
// K2: box-sum pool (window r, zero pad) + subtract cnt*mu + L2 normalize ->
// bf16 rf. Scale factors rsqrt(var) and 1/r^2 cancel under normalization.
// grid (PPAD, 32), block 256 (4 d-elements per thread). Rows >= PP -> zeros.
__global__ __launch_bounds__(256) void k2_pool(const float* __restrict__ x,
                                               const float* __restrict__ mu_acc,
                                               unsigned short* __restrict__ rf,
                                               int r) {
  const int p  = blockIdx.x;   // padded patch index
  const int lb = blockIdx.y;
  const int tid = threadIdx.x;
  const int d0 = tid * 4;
  const size_t outbase = ((size_t)lb * PPAD + p) * DD;
  if (p >= PP) {
    ushort4 z; z.x = 0; z.y = 0; z.z = 0; z.w = 0;
    *(ushort4*)(rf + outbase + d0) = z;
    return;
  }
  const float mu = mu_acc[lb] * (1.0f / ((float)PP * (float)DD));
  const int ph = p / PATCH_W, pw = p % PATCH_W;
  const int pad = r >> 1;
  float s0 = 0, s1 = 0, s2 = 0, s3 = 0;
  int cnt = 0;
  for (int dy = -pad; dy <= pad; dy++) {
    int qh = ph + dy; if (qh < 0 || qh >= PATCH_H) continue;
    for (int dx = -pad; dx <= pad; dx++) {
      int qw = pw + dx; if (qw < 0 || qw >= PATCH_W) continue;
      cnt++;
      const float* src = x + ((size_t)lb * PP + qh * PATCH_W + qw) * DD + d0;
      float4 u = *(const float4*)src;
      s0 += u.x; s1 += u.y; s2 += u.z; s3 += u.w;
    }
  }
  const float cm = (float)cnt * mu;
  s0 -= cm; s1 -= cm; s2 -= cm; s3 -= cm;
  float sq = s0 * s0 + s1 * s1 + s2 * s2 + s3 * s3;
  for (int off = 1; off < 64; off <<= 1) sq += __shfl_xor(sq, off, 64);
  __shared__ float red[4];
  if ((tid & 63) == 0) red[tid >> 6] = sq;
  __syncthreads();
  const float tot = red[0] + red[1] + red[2] + red[3];
  const float rn = rsqrtf(tot);
  ushort4 o;
  o.x = f2bf(s0 * rn); o.y = f2bf(s1 * rn); o.z = f2bf(s2 * rn); o.w = f2bf(s3 * rn);
  *(ushort4*)(rf + outbase + d0) = o;
}

// ---------------------------------------------------------------------------
// K3: per (l, unordered pair i<j): C = rf_i @ rf_j^T (1408x1408, K=1024).
// m97 structure: 128x128 block tile, 4 waves x (64x64 = 4x4 MFMA 16x16x32),
// global_load_lds width-16 staging into unpadded [128][32] LDS tiles.
// Fused epilogue: row-max -> mind[l,i,j,p], col-max -> mind[l,j,i,q] via
// atomicMax on uint encoding of (dot + 2.0) > 0.
// grid (11, 11, L_LAYERS*NPAIR), block 256.
__global__ __launch_bounds__(256) void k3_pairdots(const unsigned short* __restrict__ rf,
                                                   unsigned int* __restrict__ mind) {
  const int l = blockIdx.z / NPAIR;
  int rem = blockIdx.z % NPAIR;
  int i = 0, span = BIMG - 1;
  while (rem >= span) { rem -= span; span--; i++; }
  const int j = i + 1 + rem;

  const int rowbase = blockIdx.x * 128;
  const int colbase = blockIdx.y * 128;
  const unsigned short* A  = rf + ((size_t)(l * BIMG + i) * PPAD + rowbase) * DD;
  const unsigned short* Bp = rf + ((size_t)(l * BIMG + j) * PPAD + colbase) * DD;

  __shared__ __align__(16) unsigned short lA[128 * 32];  // 8 KB, 64 B/row
  __shared__ __align__(16) unsigned short lB[128 * 32];

  const int tid  = threadIdx.x;
  const int lane = tid & 63;
  const int wave = tid >> 6;
  const int lrow = lane & 15;
  const int quad = lane >> 4;
  const int wr = (wave >> 1) * 64;   // wave row origin within 128
  const int wc = (wave & 1) * 64;    // wave col origin within 128

  floatx4 acc[4][4];
#pragma unroll
  for (int a = 0; a < 4; a++)
#pragma unroll
    for (int b = 0; b < 4; b++) acc[a][b] = (floatx4){0.f, 0.f, 0.f, 0.f};

  // staging: each wave stages 32 rows of A and 32 of B per K-step,
  // as 2+2 global_load_lds_dwordx4 (16 rows = 1 KB per instruction).
  const int srow   = wave * 32 + (lane >> 2);   // rows for instr 0; +16 for instr 1
  const int schunk = (lane & 3) * 8;            // k offset in shorts
  const unsigned short* gA0 = A  + (size_t)srow * DD + schunk;
  const unsigned short* gA1 = gA0 + (size_t)16 * DD;
  const unsigned short* gB0 = Bp + (size_t)srow * DD + schunk;
  const unsigned short* gB1 = gB0 + (size_t)16 * DD;
  unsigned short* lA0 = lA + wave * 1024;        // uniform per wave
  unsigned short* lB0 = lB + wave * 1024;

  for (int k0 = 0; k0 < DD; k0 += 32) {
    __syncthreads();   // previous iter's fragment reads done before overwrite
    gload_lds16(gA0 + k0, lA0);
    gload_lds16(gA1 + k0, lA0 + 512);
    gload_lds16(gB0 + k0, lB0);
    gload_lds16(gB1 + k0, lB0 + 512);
    __syncthreads();   // vmcnt(0) drain at barrier -> staging visible
    bf16x8 af[4], bfv[4];
#pragma unroll
    for (int mt = 0; mt < 4; mt++)
      af[mt] = *(const bf16x8*)(lA + (wr + mt * 16 + lrow) * 32 + quad * 8);
#pragma unroll
    for (int ct = 0; ct < 4; ct++)
      bfv[ct] = *(const bf16x8*)(lB + (wc + ct * 16 + lrow) * 32 + quad * 8);
#pragma unroll
    for (int mt = 0; mt < 4; mt++)
#pragma unroll
      for (int ct = 0; ct < 4; ct++)
        acc[mt][ct] = __builtin_amdgcn_mfma_f32_16x16x32_bf16(af[mt], bfv[ct],
                                                              acc[mt][ct], 0, 0, 0);
  }

  unsigned int* mrow = mind + ((size_t)(l * BIMG + i) * BIMG + j) * PP;
  unsigned int* mcol = mind + ((size_t)(l * BIMG + j) * BIMG + i) * PP;

  // row-max over this wave's 64 cols (cols >= PP masked)
#pragma unroll
  for (int mt = 0; mt < 4; mt++) {
#pragma unroll
    for (int reg = 0; reg < 4; reg++) {
      const int gr = rowbase + wr + mt * 16 + quad * 4 + reg;
      float v = -1e30f;
#pragma unroll
      for (int ct = 0; ct < 4; ct++) {
        const int gc = colbase + wc + ct * 16 + lrow;
        if (gc < PP) v = fmaxf(v, acc[mt][ct][reg]);
      }
      for (int off = 1; off < 16; off <<= 1) v = fmaxf(v, __shfl_xor(v, off, 64));
      if (lrow == 0 && gr < PP && v > -1e29f)
        atomicMax(mrow + gr, __float_as_uint(v + 2.0f));   // dot+2 in [1,3] > 0
    }
  }
  // col-max over this wave's 64 rows (rows >= PP masked)
#pragma unroll
  for (int ct = 0; ct < 4; ct++) {
    const int gc = colbase + wc + ct * 16 + lrow;
    float v = -1e30f;
#pragma unroll
    for (int mt = 0; mt < 4; mt++) {
      const int grb = rowbase + wr + mt * 16 + quad * 4;
#pragma unroll
      for (int reg = 0; reg < 4; reg++)
        if (grb + reg < PP) v = fmaxf(v, acc[mt][ct][reg]);
    }
    for (int off = 16; off < 64; off <<= 1) v = fmaxf(v, __shfl_xor(v, off, 64));
    if (quad == 0 && gc < PP && v > -1e29f)
      atomicMax(mcol + gc, __float_as_uint(v + 2.0f));
  }
}

// ---------------------------------------------------------------------------
// K4: per (i,p): for each l, dist=sqrt(2-2*maxdot) over b!=i, mean of 2 smallest;
// accumulate (1/(L*3)) * sum_l into scores.
__global__ void k4_scores(const unsigned int* __restrict__ mind,
                          float* __restrict__ scores) {
  const int idx = blockIdx.x * 256 + threadIdx.x;
  if (idx >= BIMG * PP) return;
  const int i = idx / PP, p = idx % PP;
  float accum = 0.0f;
  for (int l = 0; l < L_LAYERS; l++) {
    float m1 = 1e30f, m2 = 1e30f;
    for (int b = 0; b < BIMG; b++) {
      if (b == i) continue;
      const unsigned int enc = mind[((size_t)(l * BIMG + i) * BIMG + b) * PP + p];
      const float dot = __uint_as_float(enc) - 2.0f;
      const float d2 = fmaxf(2.0f - 2.0f * dot, 1e-12f);
      const float dist = sqrtf(d2);
      if (dist < m1) { m2 = m1; m1 = dist; }
      else if (dist < m2) { m2 = dist; }
    }
    accum += 0.5f * (m1 + m2);
  }
  scores[idx] += accum * (1.0f / (float)(L_LAYERS * 3));
}

// ---------------------------------------------------------------------------
// K5: img_scores[i] = max_p scores[i,p].  grid 8, block 256.
__global__ void k5_imgmax(const float* __restrict__ scores, float* __restrict__ img) {
  const int i = blockIdx.x;
  float m = -1e30f;
  for (int p = threadIdx.x; p < PP; p += 256) m = fmaxf(m, scores[i * PP + p]);
  for (int off = 1; off < 64; off <<= 1) m = fmaxf(m, __shfl_xor(m, off, 64));
  __shared__ float red[4];
  if ((threadIdx.x & 63) == 0) red[threadIdx.x >> 6] = m;
  __syncthreads();
  if (threadIdx.x == 0)
    img[i] = fmaxf(fmaxf(red[0], red[1]), fmaxf(red[2], red[3]));
}

// ---------------------------------------------------------------------------
// K6: cls normalize -> sim (8x8) -> RsCIN for k=1,2,3 -> mean -> out[0:8].
// one block, 64 threads.  cls is float32.
__global__ void k6_final(const float* __restrict__ cls,
                         const float* __restrict__ img,
                         float* __restrict__ out) {
  __shared__ float norms[BIMG];
  __shared__ float sim[BIMG][BIMG];
  const int t = threadIdx.x;
  if (t < BIMG) {
    float s = 0;
    for (int d = 0; d < JJ; d++) { float v = cls[t * JJ + d]; s += v * v; }
    norms[t] = sqrtf(s);
  }
  __syncthreads();
  {
    const int ii = t >> 3, jj = t & 7;
    float s = 0;
    for (int d = 0; d < JJ; d++) s += cls[ii * JJ + d] * cls[jj * JJ + d];
    sim[ii][jj] = s / (norms[ii] * norms[jj]);
  }
  __syncthreads();
  if (t < BIMG) {
    float v[8]; int id[8];
    for (int a = 0; a < 8; a++) { v[a] = sim[t][a]; id[a] = a; }
    for (int a = 0; a < 8; a++) {            // stable selection sort, descending
      int best = a;
      for (int b = a + 1; b < 8; b++) if (v[b] > v[best]) best = b;
      float tv = v[a]; v[a] = v[best]; v[best] = tv;
      int ti = id[a]; id[a] = id[best]; id[best] = ti;
    }
    float res = 0;
    for (int k = 1; k <= 3; k++) {
      float num = 0, den = 0;
      for (int a = 0; a < k; a++) { num += v[a] * img[id[a]]; den += v[a]; }
      res += num / den;
    }
    out[t] = res * (1.0f / 3.0f);
  }
}

// ---------------------------------------------------------------------------
// K7: bilinear upsample scores (8,37,37) -> pixel (8,518,518) -> out[8:].
__global__ void k7_pixel(const float* __restrict__ scores,
                         float* __restrict__ out) {
  const int idx = blockIdx.x * 256 + threadIdx.x;
  if (idx >= BIMG * HOUT * WOUT) return;
  const int b = idx / (HOUT * WOUT);
  const int rem = idx % (HOUT * WOUT);
  const int Y = rem / WOUT, X = rem % WOUT;
  const float sy = (float)(PATCH_H - 1) / (float)(HOUT - 1);
  const float sx = (float)(PATCH_W - 1) / (float)(WOUT - 1);
  float py = (float)Y * sy;
  float px = (float)X * sx;
  int y0 = (int)floorf(py); y0 = min(max(y0, 0), PATCH_H - 1);
  int x0 = (int)floorf(px); x0 = min(max(x0, 0), PATCH_W - 1);
  const int y1 = min(y0 + 1, PATCH_H - 1);
  const int x1 = min(x0 + 1, PATCH_W - 1);
  const float wy = py - (float)y0, wx = px - (float)x0;
  const float* sc = scores + (size_t)b * PP;
  const float v =
      (1.f - wy) * ((1.f - wx) * sc[y0 * PATCH_W + x0] + wx * sc[y0 * PATCH_W + x1]) +
      wy         * ((1.f - wx) * sc[y1 * PATCH_W + x0] + wx * sc[y1 * PATCH_W + x1]);
  out[8 + idx] = v;
}

// ---------------------------------------------------------------------------
extern "C" void kernel_launch(void* const* d_in, const int* in_sizes, int n_in,
                              void* d_out, int out_size, void* d_ws, size_t ws_size,
                              hipStream_t stream) {
  const float* feat = (const float*)d_in[0];  // (4,8,1369,1024) f32
  const float* cls  = (const float*)d_in[1];  // (8,768) f32
  float* out = (float*)d_out;

  char* ws = (char*)d_ws;
  size_t off = 0;
  unsigned short* rf = (unsigned short*)(ws + off);
  off += (size_t)L_LAYERS * BIMG * PPAD * DD * 2;               // 92,274,688
  unsigned int* mind = (unsigned int*)(ws + off);
  off += (size_t)L_LAYERS * BIMG * BIMG * PP * 4;               // 1,401,856
  float* scores = (float*)(ws + off);
  off += (size_t)BIMG * PP * 4;
  float* mu_acc = (float*)(ws + off);
  off += 32 * 4;
  float* img = (float*)(ws + off);
  off += 8 * 4;

  hipMemsetAsync(mu_acc, 0, 32 * 4, stream);
  hipMemsetAsync(scores, 0, (size_t)BIMG * PP * 4, stream);
  k1_mu<<<dim3(43, 32), 256, 0, stream>>>(feat, mu_acc);

  const int rlist[3] = {1, 3, 5};
  for (int ri = 0; ri < 3; ri++) {
    k2_pool<<<dim3(PPAD, 32), 256, 0, stream>>>(feat, mu_acc, rf, rlist[ri]);
    hipMemsetAsync(mind, 0, (size_t)L_LAYERS * BIMG * BIMG * PP * 4, stream);
    k3_pairdots<<<dim3(11, 11, L_LAYERS * NPAIR), 256, 0, stream>>>(rf, mind);
    k4_scores<<<(BIMG * PP + 255) / 256, 256, 0, stream>>>(mind, scores);
  }
  k5_imgmax<<<8, 256, 0, stream>>>(scores, img);
  k6_final<<<1, 64, 0, stream>>>(cls, img, out);
  k7_pixel<<<(BIMG * HOUT * WOUT + 255) / 256, 256, 0, stream>>>(scores, out);
}

// Round 4
// 2593.826 us; speedup vs baseline: 1.5736x; 1.1283x over previous
//
#include <hip/hip_runtime.h>
#include <hip/hip_bf16.h>
#include <math.h>

#define L_LAYERS 4
#define BIMG 8
#define PATCH_H 37
#define PATCH_W 37
#define PP 1369
#define DD 1024
#define JJ 768
#define HOUT 518
#define WOUT 518
#define PPAD 1408   // 11 * 128
#define NPAIR 28

typedef float floatx4 __attribute__((ext_vector_type(4)));

// ---- software OCP e4m3fn encode/decode (RTNE) ------------------------------
__device__ __forceinline__ unsigned int f2e4m3(float v) {
  unsigned int b = __float_as_uint(v);
  unsigned int sign = (b >> 24) & 0x80u;
  float mag = fabsf(v);
  unsigned int code;
  if (mag >= 0.015625f) {                       // normal (exp >= -6)
    unsigned int mb = __float_as_uint(mag);
    mb = mb + 0x0007ffffu + ((mb >> 20) & 1u);  // RTNE to 3 mantissa bits
    code = (((mb >> 23) - 120u) << 3) | ((mb >> 20) & 7u);
  } else {                                      // denormal: quantum 2^-9
    code = (unsigned int)__float2int_rn(mag * 512.0f);  // 0..8 (8 -> 2^-6)
  }
  return code | sign;
}
__device__ __forceinline__ float e4m3tof(unsigned int c) {
  unsigned int em = c & 0x7fu;
  float m;
  if (em >= 8u) m = __uint_as_float((((em >> 3) + 120u) << 23) | ((em & 7u) << 20));
  else          m = (float)em * 0.001953125f;   // em * 2^-9
  return (c & 0x80u) ? -m : m;
}

// async global->LDS, 16B per lane; LDS dest = wave-uniform base + lane*16
__device__ __forceinline__ void gload_lds16(const void* gptr, void* lptr) {
  __builtin_amdgcn_global_load_lds(
      (const __attribute__((address_space(1))) unsigned int*)gptr,
      (__attribute__((address_space(3))) unsigned int*)lptr, 16, 0, 0);
}

// ---------------------------------------------------------------------------
// K1: per-(l,b) mean of features (float32).  grid (43, 32), block 256.
__global__ __launch_bounds__(256) void k1_mu(const float* __restrict__ x,
                                             float* __restrict__ mu_acc) {
  const int lb = blockIdx.y;
  const float* base = x + (size_t)lb * PP * DD;
  const int N4 = PP * DD / 4;   // 350464
  float s = 0.0f;
  for (int idx = blockIdx.x * 256 + threadIdx.x; idx < N4; idx += gridDim.x * 256) {
    float4 u = *(const float4*)(base + (size_t)idx * 4);
    s += u.x + u.y + u.z + u.w;
  }
  for (int off = 1; off < 64; off <<= 1) s += __shfl_xor(s, off, 64);
  __shared__ float red[4];
  if ((threadIdx.x & 63) == 0) red[threadIdx.x >> 6] = s;
  __syncthreads();
  if (threadIdx.x == 0)
    atomicAdd(&mu_acc[lb], red[0] + red[1] + red[2] + red[3]);
}

// ---------------------------------------------------------------------------
// K2: box-sum pool (window r) + subtract cnt*mu + L2 normalize -> scale x16 ->
// fp8 e4m3 rf, plus per-row norms n = sum(decoded^2) (~256).
// grid (PPAD, 32), block 256 (4 d-elements per thread). Rows >= PP -> zeros.
__global__ __launch_bounds__(256) void k2_pool(const float* __restrict__ x,
                                               const float* __restrict__ mu_acc,
                                               unsigned char* __restrict__ rf,
                                               float* __restrict__ nrm,
                                               int r) {
  const int p  = blockIdx.x;   // padded patch index
  const int lb = blockIdx.y;
  const int tid = threadIdx.x;
  const int d0 = tid * 4;
  const size_t outbase = ((size_t)lb * PPAD + p) * DD;
  if (p >= PP) {
    uchar4 z; z.x = 0; z.y = 0; z.z = 0; z.w = 0;
    *(uchar4*)(rf + outbase + d0) = z;
    if (tid == 0) nrm[(size_t)lb * PPAD + p] = 0.0f;
    return;
  }
  const float mu = mu_acc[lb] * (1.0f / ((float)PP * (float)DD));
  const int ph = p / PATCH_W, pw = p % PATCH_W;
  const int pad = r >> 1;
  float s0 = 0, s1 = 0, s2 = 0, s3 = 0;
  int cnt = 0;
  for (int dy = -pad; dy <= pad; dy++) {
    int qh = ph + dy; if (qh < 0 || qh >= PATCH_H) continue;
    for (int dx = -pad; dx <= pad; dx++) {
      int qw = pw + dx; if (qw < 0 || qw >= PATCH_W) continue;
      cnt++;
      const float* src = x + ((size_t)lb * PP + qh * PATCH_W + qw) * DD + d0;
      float4 u = *(const float4*)src;
      s0 += u.x; s1 += u.y; s2 += u.z; s3 += u.w;
    }
  }
  const float cm = (float)cnt * mu;
  s0 -= cm; s1 -= cm; s2 -= cm; s3 -= cm;
  float sq = s0 * s0 + s1 * s1 + s2 * s2 + s3 * s3;
  for (int off = 1; off < 64; off <<= 1) sq += __shfl_xor(sq, off, 64);
  __shared__ float red[4];
  if ((tid & 63) == 0) red[tid >> 6] = sq;
  __syncthreads();
  const float rn16 = rsqrtf(red[0] + red[1] + red[2] + red[3]) * 16.0f;
  unsigned int c0 = f2e4m3(s0 * rn16), c1 = f2e4m3(s1 * rn16);
  unsigned int c2 = f2e4m3(s2 * rn16), c3 = f2e4m3(s3 * rn16);
  uchar4 o; o.x = (unsigned char)c0; o.y = (unsigned char)c1;
  o.z = (unsigned char)c2; o.w = (unsigned char)c3;
  *(uchar4*)(rf + outbase + d0) = o;
  float q0 = e4m3tof(c0), q1 = e4m3tof(c1), q2 = e4m3tof(c2), q3 = e4m3tof(c3);
  float nq = q0 * q0 + q1 * q1 + q2 * q2 + q3 * q3;
  for (int off = 1; off < 64; off <<= 1) nq += __shfl_xor(nq, off, 64);
  __syncthreads();   // safe reuse of red[]
  if ((tid & 63) == 0) red[tid >> 6] = nq;
  __syncthreads();
  if (tid == 0)
    nrm[(size_t)lb * PPAD + p] = red[0] + red[1] + red[2] + red[3];
}

// ---------------------------------------------------------------------------
// K3: per (l, unordered pair i<j): S = rf_i @ rf_j^T (fp8, scaled: S=256*dot).
// 128x128 block tile, 4 waves x (64x64 = 4x4 of MFMA 16x16x32 fp8), BK=64,
// global_load_lds width-16 staging with 16B-granule XOR swizzle g^=(row>>1)&3.
// Fused epilogue (quantized-exact NN): row-max of (2S - n_j) -> mind[l,i,j,p],
// col-max of (2S - n_i) -> mind[l,j,i,q], atomicMax on uint(enc = v + 1024).
// grid (11, 11, L_LAYERS*NPAIR), block 256.
__global__ __launch_bounds__(256) void k3_pairdots(const unsigned char* __restrict__ rf,
                                                   const float* __restrict__ nrm,
                                                   unsigned int* __restrict__ mind) {
  const int l = blockIdx.z / NPAIR;
  int rem = blockIdx.z % NPAIR;
  int i = 0, span = BIMG - 1;
  while (rem >= span) { rem -= span; span--; i++; }
  const int j = i + 1 + rem;

  const int rowbase = blockIdx.x * 128;
  const int colbase = blockIdx.y * 128;
  const unsigned char* A  = rf + ((size_t)(l * BIMG + i) * PPAD + rowbase) * DD;
  const unsigned char* Bp = rf + ((size_t)(l * BIMG + j) * PPAD + colbase) * DD;

  __shared__ __align__(16) unsigned char lA[128 * 64];  // 8 KB (128 rows x 64B)
  __shared__ __align__(16) unsigned char lB[128 * 64];

  const int tid  = threadIdx.x;
  const int lane = tid & 63;
  const int wave = tid >> 6;
  const int lrow = lane & 15;
  const int quad = lane >> 4;
  const int wr = (wave >> 1) * 64;   // wave row origin within 128
  const int wc = (wave & 1) * 64;    // wave col origin within 128

  floatx4 acc[4][4];
#pragma unroll
  for (int a = 0; a < 4; a++)
#pragma unroll
    for (int b = 0; b < 4; b++) acc[a][b] = (floatx4){0.f, 0.f, 0.f, 0.f};

  // staging: per K-64 step each wave stages its 32-row strip of A and B as
  // 2+2 global_load_lds_dwordx4.  Lane covers (row = base + lane>>2,
  // physical granule = lane&3) which holds global granule (lane&3)^swz(row).
  const int r0  = wave * 32 + (lane >> 2);           // rows r0 and r0+16
  const int gsw = (lane & 3) ^ ((lane >> 3) & 3);    // swz(r0) == swz(r0+16)
  const unsigned char* gA0 = A  + (size_t)r0 * DD + gsw * 16;
  const unsigned char* gA1 = gA0 + (size_t)16 * DD;
  const unsigned char* gB0 = Bp + (size_t)r0 * DD + gsw * 16;
  const unsigned char* gB1 = gB0 + (size_t)16 * DD;
  unsigned char* dA0 = lA + wave * 2048;
  unsigned char* dA1 = dA0 + 1024;
  unsigned char* dB0 = lB + wave * 2048;
  unsigned char* dB1 = dB0 + 1024;

  const int swf = (lrow >> 1) & 3;                   // fragment-read swizzle key
  const int sub8 = (quad & 1) * 8;
  int rowoffA[4], rowoffB[4];
#pragma unroll
  for (int t = 0; t < 4; t++) {
    rowoffA[t] = (wr + t * 16 + lrow) * 64 + sub8;
    rowoffB[t] = (wc + t * 16 + lrow) * 64 + sub8;
  }

  for (int k0 = 0; k0 < DD; k0 += 64) {
    __syncthreads();   // previous sub-steps' fragment reads done
    gload_lds16(gA0 + k0, dA0);
    gload_lds16(gA1 + k0, dA1);
    gload_lds16(gB0 + k0, dB0);
    gload_lds16(gB1 + k0, dB1);
    __syncthreads();   // staging visible
#pragma unroll
    for (int ks = 0; ks < 2; ks++) {
      const int gfrag = (((ks << 1) + (quad >> 1)) ^ swf) * 16;
      long af[4], bfv[4];
#pragma unroll
      for (int mt = 0; mt < 4; mt++)
        af[mt] = *(const long*)(lA + rowoffA[mt] + gfrag);
#pragma unroll
      for (int ct = 0; ct < 4; ct++)
        bfv[ct] = *(const long*)(lB + rowoffB[ct] + gfrag);
#pragma unroll
      for (int mt = 0; mt < 4; mt++)
#pragma unroll
        for (int ct = 0; ct < 4; ct++)
          acc[mt][ct] = __builtin_amdgcn_mfma_f32_16x16x32_fp8_fp8(
              af[mt], bfv[ct], acc[mt][ct], 0, 0, 0);
    }
  }

  const float* nI = nrm + (size_t)(l * BIMG + i) * PPAD;
  const float* nJ = nrm + (size_t)(l * BIMG + j) * PPAD;
  unsigned int* mrow = mind + ((size_t)(l * BIMG + i) * BIMG + j) * PP;
  unsigned int* mcol = mind + ((size_t)(l * BIMG + j) * BIMG + i) * PP;

  float nj[4];
#pragma unroll
  for (int ct = 0; ct < 4; ct++) nj[ct] = nJ[colbase + wc + ct * 16 + lrow];
  float ni[4][4];
#pragma unroll
  for (int mt = 0; mt < 4; mt++)
#pragma unroll
    for (int reg = 0; reg < 4; reg++)
      ni[mt][reg] = nI[rowbase + wr + mt * 16 + quad * 4 + reg];

  // row-max of (2S - n_j) over this wave's 64 cols
#pragma unroll
  for (int mt = 0; mt < 4; mt++) {
#pragma unroll
    for (int reg = 0; reg < 4; reg++) {
      const int gr = rowbase + wr + mt * 16 + quad * 4 + reg;
      float v = -1e30f;
#pragma unroll
      for (int ct = 0; ct < 4; ct++) {
        const int gc = colbase + wc + ct * 16 + lrow;
        if (gc < PP) v = fmaxf(v, 2.0f * acc[mt][ct][reg] - nj[ct]);
      }
      for (int off = 1; off < 16; off <<= 1) v = fmaxf(v, __shfl_xor(v, off, 64));
      if (lrow == 0 && gr < PP)
        atomicMax(mrow + gr, __float_as_uint(v + 1024.0f));
    }
  }
  // col-max of (2S - n_i) over this wave's 64 rows
#pragma unroll
  for (int ct = 0; ct < 4; ct++) {
    const int gc = colbase + wc + ct * 16 + lrow;
    float v = -1e30f;
#pragma unroll
    for (int mt = 0; mt < 4; mt++) {
      const int grb = rowbase + wr + mt * 16 + quad * 4;
#pragma unroll
      for (int reg = 0; reg < 4; reg++)
        if (grb + reg < PP) v = fmaxf(v, 2.0f * acc[mt][ct][reg] - ni[mt][reg]);
    }
    for (int off = 16; off < 64; off <<= 1) v = fmaxf(v, __shfl_xor(v, off, 64));
    if (quad == 0 && gc < PP)
      atomicMax(mcol + gc, __float_as_uint(v + 1024.0f));
  }
}

// ---------------------------------------------------------------------------
// K4: per (i,p): for each l, d2 = (n_own - max(2S - n_other)) / 256 over b!=i,
// dist = sqrt(max(d2,1e-12)); mean of 2 smallest; accumulate into scores.
__global__ void k4_scores(const unsigned int* __restrict__ mind,
                          const float* __restrict__ nrm,
                          float* __restrict__ scores) {
  const int idx = blockIdx.x * 256 + threadIdx.x;
  if (idx >= BIMG * PP) return;
  const int i = idx / PP, p = idx % PP;
  float accum = 0.0f;
  for (int l = 0; l < L_LAYERS; l++) {
    const float n_own = nrm[(size_t)(l * BIMG + i) * PPAD + p];
    float m1 = 1e30f, m2 = 1e30f;
    for (int b = 0; b < BIMG; b++) {
      if (b == i) continue;
      const unsigned int enc = mind[((size_t)(l * BIMG + i) * BIMG + b) * PP + p];
      const float val = __uint_as_float(enc) - 1024.0f;   // max(2S - n_other)
      const float d2 = fmaxf((n_own - val) * (1.0f / 256.0f), 1e-12f);
      const float dist = sqrtf(d2);
      if (dist < m1) { m2 = m1; m1 = dist; }
      else if (dist < m2) { m2 = dist; }
    }
    accum += 0.5f * (m1 + m2);
  }
  scores[idx] += accum * (1.0f / (float)(L_LAYERS * 3));
}

// ---------------------------------------------------------------------------
// K5: img_scores[i] = max_p scores[i,p].  grid 8, block 256.
__global__ void k5_imgmax(const float* __restrict__ scores, float* __restrict__ img) {
  const int i = blockIdx.x;
  float m = -1e30f;
  for (int p = threadIdx.x; p < PP; p += 256) m = fmaxf(m, scores[i * PP + p]);
  for (int off = 1; off < 64; off <<= 1) m = fmaxf(m, __shfl_xor(m, off, 64));
  __shared__ float red[4];
  if ((threadIdx.x & 63) == 0) red[threadIdx.x >> 6] = m;
  __syncthreads();
  if (threadIdx.x == 0)
    img[i] = fmaxf(fmaxf(red[0], red[1]), fmaxf(red[2], red[3]));
}

// ---------------------------------------------------------------------------
// K6: cls normalize -> sim (8x8) -> RsCIN for k=1,2,3 -> mean -> out[0:8].
__global__ void k6_final(const float* __restrict__ cls,
                         const float* __restrict__ img,
                         float* __restrict__ out) {
  __shared__ float norms[BIMG];
  __shared__ float sim[BIMG][BIMG];
  const int t = threadIdx.x;
  if (t < BIMG) {
    float s = 0;
    for (int d = 0; d < JJ; d++) { float v = cls[t * JJ + d]; s += v * v; }
    norms[t] = sqrtf(s);
  }
  __syncthreads();
  {
    const int ii = t >> 3, jj = t & 7;
    float s = 0;
    for (int d = 0; d < JJ; d++) s += cls[ii * JJ + d] * cls[jj * JJ + d];
    sim[ii][jj] = s / (norms[ii] * norms[jj]);
  }
  __syncthreads();
  if (t < BIMG) {
    float v[8]; int id[8];
    for (int a = 0; a < 8; a++) { v[a] = sim[t][a]; id[a] = a; }
    for (int a = 0; a < 8; a++) {            // stable selection sort, descending
      int best = a;
      for (int b = a + 1; b < 8; b++) if (v[b] > v[best]) best = b;
      float tv = v[a]; v[a] = v[best]; v[best] = tv;
      int ti = id[a]; id[a] = id[best]; id[best] = ti;
    }
    float res = 0;
    for (int k = 1; k <= 3; k++) {
      float num = 0, den = 0;
      for (int a = 0; a < k; a++) { num += v[a] * img[id[a]]; den += v[a]; }
      res += num / den;
    }
    out[t] = res * (1.0f / 3.0f);
  }
}

// ---------------------------------------------------------------------------
// K7: bilinear upsample scores (8,37,37) -> pixel (8,518,518) -> out[8:].
__global__ void k7_pixel(const float* __restrict__ scores,
                         float* __restrict__ out) {
  const int idx = blockIdx.x * 256 + threadIdx.x;
  if (idx >= BIMG * HOUT * WOUT) return;
  const int b = idx / (HOUT * WOUT);
  const int rem = idx % (HOUT * WOUT);
  const int Y = rem / WOUT, X = rem % WOUT;
  const float sy = (float)(PATCH_H - 1) / (float)(HOUT - 1);
  const float sx = (float)(PATCH_W - 1) / (float)(WOUT - 1);
  float py = (float)Y * sy;
  float px = (float)X * sx;
  int y0 = (int)floorf(py); y0 = min(max(y0, 0), PATCH_H - 1);
  int x0 = (int)floorf(px); x0 = min(max(x0, 0), PATCH_W - 1);
  const int y1 = min(y0 + 1, PATCH_H - 1);
  const int x1 = min(x0 + 1, PATCH_W - 1);
  const float wy = py - (float)y0, wx = px - (float)x0;
  const float* sc = scores + (size_t)b * PP;
  const float v =
      (1.f - wy) * ((1.f - wx) * sc[y0 * PATCH_W + x0] + wx * sc[y0 * PATCH_W + x1]) +
      wy         * ((1.f - wx) * sc[y1 * PATCH_W + x0] + wx * sc[y1 * PATCH_W + x1]);
  out[8 + idx] = v;
}

// ---------------------------------------------------------------------------
extern "C" void kernel_launch(void* const* d_in, const int* in_sizes, int n_in,
                              void* d_out, int out_size, void* d_ws, size_t ws_size,
                              hipStream_t stream) {
  const float* feat = (const float*)d_in[0];  // (4,8,1369,1024) f32
  const float* cls  = (const float*)d_in[1];  // (8,768) f32
  float* out = (float*)d_out;

  char* ws = (char*)d_ws;
  size_t off = 0;
  unsigned char* rf = (unsigned char*)(ws + off);
  off += (size_t)L_LAYERS * BIMG * PPAD * DD;                   // 46,137,344
  unsigned int* mind = (unsigned int*)(ws + off);
  off += (size_t)L_LAYERS * BIMG * BIMG * PP * 4;               // 1,401,856
  float* nrm = (float*)(ws + off);
  off += (size_t)L_LAYERS * BIMG * PPAD * 4;                    // 180,224
  float* scores = (float*)(ws + off);
  off += (size_t)BIMG * PP * 4;
  float* mu_acc = (float*)(ws + off);
  off += 32 * 4;
  float* img = (float*)(ws + off);
  off += 8 * 4;

  hipMemsetAsync(mu_acc, 0, 32 * 4, stream);
  hipMemsetAsync(scores, 0, (size_t)BIMG * PP * 4, stream);
  k1_mu<<<dim3(43, 32), 256, 0, stream>>>(feat, mu_acc);

  const int rlist[3] = {1, 3, 5};
  for (int ri = 0; ri < 3; ri++) {
    k2_pool<<<dim3(PPAD, 32), 256, 0, stream>>>(feat, mu_acc, rf, nrm, rlist[ri]);
    hipMemsetAsync(mind, 0, (size_t)L_LAYERS * BIMG * BIMG * PP * 4, stream);
    k3_pairdots<<<dim3(11, 11, L_LAYERS * NPAIR), 256, 0, stream>>>(rf, nrm, mind);
    k4_scores<<<(BIMG * PP + 255) / 256, 256, 0, stream>>>(mind, nrm, scores);
  }
  k5_imgmax<<<8, 256, 0, stream>>>(scores, img);
  k6_final<<<1, 64, 0, stream>>>(cls, img, out);
  k7_pixel<<<(BIMG * HOUT * WOUT + 255) / 256, 256, 0, stream>>>(scores, out);
}

// Round 5
// 2564.784 us; speedup vs baseline: 1.5914x; 1.0113x over previous
//
#include <hip/hip_runtime.h>
#include <hip/hip_bf16.h>
#include <math.h>

#define L_LAYERS 4
#define BIMG 8
#define PATCH_H 37
#define PATCH_W 37
#define PP 1369
#define DD 1024
#define JJ 768
#define HOUT 518
#define WOUT 518
#define PPAD 1408   // 11 * 128
#define NPAIR 28
#define ZPAIR (L_LAYERS * NPAIR)          // 112
#define RFSZ  ((size_t)L_LAYERS * BIMG * PPAD * DD)    // bytes (fp8) = 46,137,344
#define NRMSZ ((size_t)L_LAYERS * BIMG * PPAD)         // floats
#define MINDSZ ((size_t)L_LAYERS * BIMG * BIMG * PP)   // uints

typedef float floatx4 __attribute__((ext_vector_type(4)));

// ---- software OCP e4m3fn encode/decode (RTNE) ------------------------------
__device__ __forceinline__ unsigned int f2e4m3(float v) {
  unsigned int b = __float_as_uint(v);
  unsigned int sign = (b >> 24) & 0x80u;
  float mag = fabsf(v);
  unsigned int code;
  if (mag >= 0.015625f) {                       // normal (exp >= -6)
    unsigned int mb = __float_as_uint(mag);
    mb = mb + 0x0007ffffu + ((mb >> 20) & 1u);  // RTNE to 3 mantissa bits
    code = (((mb >> 23) - 120u) << 3) | ((mb >> 20) & 7u);
  } else {                                      // denormal: quantum 2^-9
    code = (unsigned int)__float2int_rn(mag * 512.0f);
  }
  return code | sign;
}
__device__ __forceinline__ float e4m3tof(unsigned int c) {
  unsigned int em = c & 0x7fu;
  float m;
  if (em >= 8u) m = __uint_as_float((((em >> 3) + 120u) << 23) | ((em & 7u) << 20));
  else          m = (float)em * 0.001953125f;
  return (c & 0x80u) ? -m : m;
}

// async global->LDS, 16B per lane; LDS dest = wave-uniform base + lane*16
__device__ __forceinline__ void gload_lds16(const void* gptr, void* lptr) {
  __builtin_amdgcn_global_load_lds(
      (const __attribute__((address_space(1))) unsigned int*)gptr,
      (__attribute__((address_space(3))) unsigned int*)lptr, 16, 0, 0);
}

// ---------------------------------------------------------------------------
// K1: per-(l,b) mean of features (float32).  grid (43, 32), block 256.
__global__ __launch_bounds__(256) void k1_mu(const float* __restrict__ x,
                                             float* __restrict__ mu_acc) {
  const int lb = blockIdx.y;
  const float* base = x + (size_t)lb * PP * DD;
  const int N4 = PP * DD / 4;
  float s = 0.0f;
  for (int idx = blockIdx.x * 256 + threadIdx.x; idx < N4; idx += gridDim.x * 256) {
    float4 u = *(const float4*)(base + (size_t)idx * 4);
    s += u.x + u.y + u.z + u.w;
  }
  for (int off = 1; off < 64; off <<= 1) s += __shfl_xor(s, off, 64);
  __shared__ float red[4];
  if ((threadIdx.x & 63) == 0) red[threadIdx.x >> 6] = s;
  __syncthreads();
  if (threadIdx.x == 0)
    atomicAdd(&mu_acc[lb], red[0] + red[1] + red[2] + red[3]);
}

// ---------------------------------------------------------------------------
// shared finisher: subtract cnt*mu, block-L2-normalize, x16, fp8-encode, store
__device__ __forceinline__ void finish_r(float s0, float s1, float s2, float s3,
                                         float cm, unsigned char* dst, float* nrmdst,
                                         int tid, float* red) {
  s0 -= cm; s1 -= cm; s2 -= cm; s3 -= cm;
  float sq = s0 * s0 + s1 * s1 + s2 * s2 + s3 * s3;
  for (int off = 1; off < 64; off <<= 1) sq += __shfl_xor(sq, off, 64);
  __syncthreads();
  if ((tid & 63) == 0) red[tid >> 6] = sq;
  __syncthreads();
  const float rn16 = rsqrtf(red[0] + red[1] + red[2] + red[3]) * 16.0f;
  unsigned int c0 = f2e4m3(s0 * rn16), c1 = f2e4m3(s1 * rn16);
  unsigned int c2 = f2e4m3(s2 * rn16), c3 = f2e4m3(s3 * rn16);
  uchar4 o; o.x = (unsigned char)c0; o.y = (unsigned char)c1;
  o.z = (unsigned char)c2; o.w = (unsigned char)c3;
  *(uchar4*)dst = o;
  float q0 = e4m3tof(c0), q1 = e4m3tof(c1), q2 = e4m3tof(c2), q3 = e4m3tof(c3);
  float nq = q0 * q0 + q1 * q1 + q2 * q2 + q3 * q3;
  for (int off = 1; off < 64; off <<= 1) nq += __shfl_xor(nq, off, 64);
  __syncthreads();
  if ((tid & 63) == 0) red[tid >> 6] = nq;
  __syncthreads();
  if (tid == 0) *nrmdst = red[0] + red[1] + red[2] + red[3];
}

// K2f: fused pool for r=1,3,5 from one 5x5 read.  grid (PPAD, 32), block 256.
__global__ __launch_bounds__(256) void k2_pool3(const float* __restrict__ x,
                                                const float* __restrict__ mu_acc,
                                                unsigned char* __restrict__ rf,
                                                float* __restrict__ nrm) {
  const int p  = blockIdx.x;
  const int lb = blockIdx.y;
  const int tid = threadIdx.x;
  const int d0 = tid * 4;
  const size_t outoff = ((size_t)lb * PPAD + p) * DD + d0;
  if (p >= PP) {
    uchar4 z; z.x = 0; z.y = 0; z.z = 0; z.w = 0;
    for (int r = 0; r < 3; r++) {
      *(uchar4*)(rf + r * RFSZ + outoff) = z;
      if (tid == 0) nrm[r * NRMSZ + (size_t)lb * PPAD + p] = 0.0f;
    }
    return;
  }
  const float mu = mu_acc[lb] * (1.0f / ((float)PP * (float)DD));
  const int ph = p / PATCH_W, pw = p % PATCH_W;
  float a5[4] = {0, 0, 0, 0}, a3[4] = {0, 0, 0, 0}, a1[4] = {0, 0, 0, 0};
  int c5 = 0, c3 = 0;
  for (int dy = -2; dy <= 2; dy++) {
    int qh = ph + dy; if (qh < 0 || qh >= PATCH_H) continue;
    for (int dx = -2; dx <= 2; dx++) {
      int qw = pw + dx; if (qw < 0 || qw >= PATCH_W) continue;
      const float* src = x + ((size_t)lb * PP + qh * PATCH_W + qw) * DD + d0;
      float4 u = *(const float4*)src;
      a5[0] += u.x; a5[1] += u.y; a5[2] += u.z; a5[3] += u.w; c5++;
      if (dy >= -1 && dy <= 1 && dx >= -1 && dx <= 1) {
        a3[0] += u.x; a3[1] += u.y; a3[2] += u.z; a3[3] += u.w; c3++;
        if (dy == 0 && dx == 0) { a1[0] = u.x; a1[1] = u.y; a1[2] = u.z; a1[3] = u.w; }
      }
    }
  }
  __shared__ float red[4];
  const size_t noff = (size_t)lb * PPAD + p;
  finish_r(a1[0], a1[1], a1[2], a1[3], mu, rf + outoff, nrm + noff, tid, red);
  finish_r(a3[0], a3[1], a3[2], a3[3], (float)c3 * mu, rf + RFSZ + outoff,
           nrm + NRMSZ + noff, tid, red);
  finish_r(a5[0], a5[1], a5[2], a5[3], (float)c5 * mu, rf + 2 * RFSZ + outoff,
           nrm + 2 * NRMSZ + noff, tid, red);
}

// K2s: single-r pool (fallback path).  grid (PPAD, 32), block 256.
__global__ __launch_bounds__(256) void k2_pool(const float* __restrict__ x,
                                               const float* __restrict__ mu_acc,
                                               unsigned char* __restrict__ rf,
                                               float* __restrict__ nrm, int r) {
  const int p  = blockIdx.x;
  const int lb = blockIdx.y;
  const int tid = threadIdx.x;
  const int d0 = tid * 4;
  const size_t outoff = ((size_t)lb * PPAD + p) * DD + d0;
  if (p >= PP) {
    uchar4 z; z.x = 0; z.y = 0; z.z = 0; z.w = 0;
    *(uchar4*)(rf + outoff) = z;
    if (tid == 0) nrm[(size_t)lb * PPAD + p] = 0.0f;
    return;
  }
  const float mu = mu_acc[lb] * (1.0f / ((float)PP * (float)DD));
  const int ph = p / PATCH_W, pw = p % PATCH_W;
  const int pad = r >> 1;
  float s0 = 0, s1 = 0, s2 = 0, s3 = 0;
  int cnt = 0;
  for (int dy = -pad; dy <= pad; dy++) {
    int qh = ph + dy; if (qh < 0 || qh >= PATCH_H) continue;
    for (int dx = -pad; dx <= pad; dx++) {
      int qw = pw + dx; if (qw < 0 || qw >= PATCH_W) continue;
      cnt++;
      const float* src = x + ((size_t)lb * PP + qh * PATCH_W + qw) * DD + d0;
      float4 u = *(const float4*)src;
      s0 += u.x; s1 += u.y; s2 += u.z; s3 += u.w;
    }
  }
  __shared__ float red[4];
  finish_r(s0, s1, s2, s3, (float)cnt * mu, rf + outoff,
           nrm + (size_t)lb * PPAD + p, tid, red);
}

// ---------------------------------------------------------------------------
// K3: per (rsel, l, pair i<j): S = rf_i @ rf_j^T (fp8, S = 256*dot).
// 128x128 tile, 4 waves x 4x4 MFMA 16x16x32 fp8, BK=64, global_load_lds
// staging with 16B-granule XOR swizzle.  Fused epilogue: row/col max of
// (2S - n_other) via atomicMax(uint(v+1024)).
// grid (11, 11, nz*112), block 256, 3 blocks/CU.
__global__ __launch_bounds__(256, 3) void k3_pairdots(const unsigned char* __restrict__ rf,
                                                      const float* __restrict__ nrm,
                                                      unsigned int* __restrict__ mind) {
  const int rsel = blockIdx.z / ZPAIR;
  const int zz   = blockIdx.z % ZPAIR;
  const int l = zz / NPAIR;
  int rem = zz % NPAIR;
  int i = 0, span = BIMG - 1;
  while (rem >= span) { rem -= span; span--; i++; }
  const int j = i + 1 + rem;

  const unsigned char* rfr = rf + (size_t)rsel * RFSZ;
  const int rowbase = blockIdx.x * 128;
  const int colbase = blockIdx.y * 128;
  const unsigned char* A  = rfr + ((size_t)(l * BIMG + i) * PPAD + rowbase) * DD;
  const unsigned char* Bp = rfr + ((size_t)(l * BIMG + j) * PPAD + colbase) * DD;

  __shared__ __align__(16) unsigned char lA[128 * 64];  // 8 KB
  __shared__ __align__(16) unsigned char lB[128 * 64];

  const int tid  = threadIdx.x;
  const int lane = tid & 63;
  const int wave = tid >> 6;
  const int lrow = lane & 15;
  const int quad = lane >> 4;
  const int wr = (wave >> 1) * 64;
  const int wc = (wave & 1) * 64;

  floatx4 acc[4][4];
#pragma unroll
  for (int a = 0; a < 4; a++)
#pragma unroll
    for (int b = 0; b < 4; b++) acc[a][b] = (floatx4){0.f, 0.f, 0.f, 0.f};

  // staging: lane covers (row = wave*32 + lane>>2 [+16], physical granule
  // lane&3) holding global granule (lane&3)^((row>>1)&3).
  const int r0  = wave * 32 + (lane >> 2);
  const int gsw = (lane & 3) ^ ((lane >> 3) & 3);
  const size_t goff = (size_t)r0 * DD + gsw * 16;   // same for A and B
  unsigned char* dA0 = lA + wave * 2048;
  unsigned char* dB0 = lB + wave * 2048;

  const int swf = (lrow >> 1) & 3;
  const int sub8 = (quad & 1) * 8;

  for (int k0 = 0; k0 < DD; k0 += 64) {
    __syncthreads();
    gload_lds16(A + goff + k0, dA0);
    gload_lds16(A + goff + 16 * DD + k0, dA0 + 1024);
    gload_lds16(Bp + goff + k0, dB0);
    gload_lds16(Bp + goff + 16 * DD + k0, dB0 + 1024);
    __syncthreads();
#pragma unroll
    for (int ks = 0; ks < 2; ks++) {
      const int gfrag = (((ks << 1) + (quad >> 1)) ^ swf) * 16 + sub8;
      long af[4], bfv[4];
#pragma unroll
      for (int mt = 0; mt < 4; mt++)
        af[mt] = *(const long*)(lA + (wr + mt * 16 + lrow) * 64 + gfrag);
#pragma unroll
      for (int ct = 0; ct < 4; ct++)
        bfv[ct] = *(const long*)(lB + (wc + ct * 16 + lrow) * 64 + gfrag);
#pragma unroll
      for (int mt = 0; mt < 4; mt++)
#pragma unroll
        for (int ct = 0; ct < 4; ct++)
          acc[mt][ct] = __builtin_amdgcn_mfma_f32_16x16x32_fp8_fp8(
              af[mt], bfv[ct], acc[mt][ct], 0, 0, 0);
    }
  }

  const float* nI = nrm + rsel * NRMSZ + (size_t)(l * BIMG + i) * PPAD;
  const float* nJ = nrm + rsel * NRMSZ + (size_t)(l * BIMG + j) * PPAD;
  unsigned int* mrow = mind + rsel * MINDSZ + ((size_t)(l * BIMG + i) * BIMG + j) * PP;
  unsigned int* mcol = mind + rsel * MINDSZ + ((size_t)(l * BIMG + j) * BIMG + i) * PP;

  // row-max of (2S - n_j)
#pragma unroll
  for (int mt = 0; mt < 4; mt++) {
#pragma unroll
    for (int reg = 0; reg < 4; reg++) {
      const int gr = rowbase + wr + mt * 16 + quad * 4 + reg;
      float v = -1e30f;
#pragma unroll
      for (int ct = 0; ct < 4; ct++) {
        const int gc = colbase + wc + ct * 16 + lrow;
        if (gc < PP) v = fmaxf(v, 2.0f * acc[mt][ct][reg] - nJ[gc]);
      }
      for (int off = 1; off < 16; off <<= 1) v = fmaxf(v, __shfl_xor(v, off, 64));
      if (lrow == 0 && gr < PP)
        atomicMax(mrow + gr, __float_as_uint(v + 1024.0f));
    }
  }
  // col-max of (2S - n_i)
#pragma unroll
  for (int ct = 0; ct < 4; ct++) {
    const int gc = colbase + wc + ct * 16 + lrow;
    float v = -1e30f;
#pragma unroll
    for (int mt = 0; mt < 4; mt++) {
      const int grb = rowbase + wr + mt * 16 + quad * 4;
#pragma unroll
      for (int reg = 0; reg < 4; reg++)
        if (grb + reg < PP) v = fmaxf(v, 2.0f * acc[mt][ct][reg] - nI[grb + reg]);
    }
    for (int off = 16; off < 64; off <<= 1) v = fmaxf(v, __shfl_xor(v, off, 64));
    if (quad == 0 && gc < PP)
      atomicMax(mcol + gc, __float_as_uint(v + 1024.0f));
  }
}

// ---------------------------------------------------------------------------
// K4: per (i,p): over nr r-buffers and L layers, d2=(n_own - max(2S-n_other))/256,
// dist=sqrt; mean of 2 smallest over b!=i; accumulate into scores.
__global__ void k4_scores(const unsigned int* __restrict__ mind,
                          const float* __restrict__ nrm,
                          float* __restrict__ scores, int nr) {
  const int idx = blockIdx.x * 256 + threadIdx.x;
  if (idx >= BIMG * PP) return;
  const int i = idx / PP, p = idx % PP;
  float accum = 0.0f;
  for (int r = 0; r < nr; r++) {
    for (int l = 0; l < L_LAYERS; l++) {
      const float n_own = nrm[r * NRMSZ + (size_t)(l * BIMG + i) * PPAD + p];
      float m1 = 1e30f, m2 = 1e30f;
      for (int b = 0; b < BIMG; b++) {
        if (b == i) continue;
        const unsigned int enc =
            mind[r * MINDSZ + ((size_t)(l * BIMG + i) * BIMG + b) * PP + p];
        const float val = __uint_as_float(enc) - 1024.0f;
        const float d2 = fmaxf((n_own - val) * (1.0f / 256.0f), 1e-12f);
        const float dist = sqrtf(d2);
        if (dist < m1) { m2 = m1; m1 = dist; }
        else if (dist < m2) { m2 = dist; }
      }
      accum += 0.5f * (m1 + m2);
    }
  }
  scores[idx] += accum * (1.0f / (float)(L_LAYERS * 3));
}

// ---------------------------------------------------------------------------
__global__ void k5_imgmax(const float* __restrict__ scores, float* __restrict__ img) {
  const int i = blockIdx.x;
  float m = -1e30f;
  for (int p = threadIdx.x; p < PP; p += 256) m = fmaxf(m, scores[i * PP + p]);
  for (int off = 1; off < 64; off <<= 1) m = fmaxf(m, __shfl_xor(m, off, 64));
  __shared__ float red[4];
  if ((threadIdx.x & 63) == 0) red[threadIdx.x >> 6] = m;
  __syncthreads();
  if (threadIdx.x == 0)
    img[i] = fmaxf(fmaxf(red[0], red[1]), fmaxf(red[2], red[3]));
}

// ---------------------------------------------------------------------------
__global__ void k6_final(const float* __restrict__ cls,
                         const float* __restrict__ img,
                         float* __restrict__ out) {
  __shared__ float norms[BIMG];
  __shared__ float sim[BIMG][BIMG];
  const int t = threadIdx.x;
  if (t < BIMG) {
    float s = 0;
    for (int d = 0; d < JJ; d++) { float v = cls[t * JJ + d]; s += v * v; }
    norms[t] = sqrtf(s);
  }
  __syncthreads();
  {
    const int ii = t >> 3, jj = t & 7;
    float s = 0;
    for (int d = 0; d < JJ; d++) s += cls[ii * JJ + d] * cls[jj * JJ + d];
    sim[ii][jj] = s / (norms[ii] * norms[jj]);
  }
  __syncthreads();
  if (t < BIMG) {
    float v[8]; int id[8];
    for (int a = 0; a < 8; a++) { v[a] = sim[t][a]; id[a] = a; }
    for (int a = 0; a < 8; a++) {
      int best = a;
      for (int b = a + 1; b < 8; b++) if (v[b] > v[best]) best = b;
      float tv = v[a]; v[a] = v[best]; v[best] = tv;
      int ti = id[a]; id[a] = id[best]; id[best] = ti;
    }
    float res = 0;
    for (int k = 1; k <= 3; k++) {
      float num = 0, den = 0;
      for (int a = 0; a < k; a++) { num += v[a] * img[id[a]]; den += v[a]; }
      res += num / den;
    }
    out[t] = res * (1.0f / 3.0f);
  }
}

// ---------------------------------------------------------------------------
__global__ void k7_pixel(const float* __restrict__ scores,
                         float* __restrict__ out) {
  const int idx = blockIdx.x * 256 + threadIdx.x;
  if (idx >= BIMG * HOUT * WOUT) return;
  const int b = idx / (HOUT * WOUT);
  const int rem = idx % (HOUT * WOUT);
  const int Y = rem / WOUT, X = rem % WOUT;
  const float sy = (float)(PATCH_H - 1) / (float)(HOUT - 1);
  const float sx = (float)(PATCH_W - 1) / (float)(WOUT - 1);
  float py = (float)Y * sy;
  float px = (float)X * sx;
  int y0 = (int)floorf(py); y0 = min(max(y0, 0), PATCH_H - 1);
  int x0 = (int)floorf(px); x0 = min(max(x0, 0), PATCH_W - 1);
  const int y1 = min(y0 + 1, PATCH_H - 1);
  const int x1 = min(x0 + 1, PATCH_W - 1);
  const float wy = py - (float)y0, wx = px - (float)x0;
  const float* sc = scores + (size_t)b * PP;
  const float v =
      (1.f - wy) * ((1.f - wx) * sc[y0 * PATCH_W + x0] + wx * sc[y0 * PATCH_W + x1]) +
      wy         * ((1.f - wx) * sc[y1 * PATCH_W + x0] + wx * sc[y1 * PATCH_W + x1]);
  out[8 + idx] = v;
}

// ---------------------------------------------------------------------------
extern "C" void kernel_launch(void* const* d_in, const int* in_sizes, int n_in,
                              void* d_out, int out_size, void* d_ws, size_t ws_size,
                              hipStream_t stream) {
  const float* feat = (const float*)d_in[0];  // (4,8,1369,1024) f32
  const float* cls  = (const float*)d_in[1];  // (8,768) f32
  float* out = (float*)d_out;

  const size_t need_fused = 3 * RFSZ + 3 * MINDSZ * 4 + 3 * NRMSZ * 4 +
                            (size_t)BIMG * PP * 4 + 1024;
  const bool fused = ws_size >= need_fused;

  char* ws = (char*)d_ws;
  size_t off = 0;
  unsigned char* rf = (unsigned char*)(ws + off);
  off += (fused ? 3 : 1) * RFSZ;
  unsigned int* mind = (unsigned int*)(ws + off);
  off += (fused ? 3 : 1) * MINDSZ * 4;
  float* nrm = (float*)(ws + off);
  off += (fused ? 3 : 1) * NRMSZ * 4;
  float* scores = (float*)(ws + off);
  off += (size_t)BIMG * PP * 4;
  float* mu_acc = (float*)(ws + off);
  off += 32 * 4;
  float* img = (float*)(ws + off);
  off += 8 * 4;

  hipMemsetAsync(mu_acc, 0, 32 * 4, stream);
  hipMemsetAsync(scores, 0, (size_t)BIMG * PP * 4, stream);
  k1_mu<<<dim3(43, 32), 256, 0, stream>>>(feat, mu_acc);

  if (fused) {
    k2_pool3<<<dim3(PPAD, 32), 256, 0, stream>>>(feat, mu_acc, rf, nrm);
    hipMemsetAsync(mind, 0, 3 * MINDSZ * 4, stream);
    k3_pairdots<<<dim3(11, 11, 3 * ZPAIR), 256, 0, stream>>>(rf, nrm, mind);
    k4_scores<<<(BIMG * PP + 255) / 256, 256, 0, stream>>>(mind, nrm, scores, 3);
  } else {
    const int rlist[3] = {1, 3, 5};
    for (int ri = 0; ri < 3; ri++) {
      k2_pool<<<dim3(PPAD, 32), 256, 0, stream>>>(feat, mu_acc, rf, nrm, rlist[ri]);
      hipMemsetAsync(mind, 0, MINDSZ * 4, stream);
      k3_pairdots<<<dim3(11, 11, ZPAIR), 256, 0, stream>>>(rf, nrm, mind);
      k4_scores<<<(BIMG * PP + 255) / 256, 256, 0, stream>>>(mind, nrm, scores, 1);
    }
  }
  k5_imgmax<<<8, 256, 0, stream>>>(scores, img);
  k6_final<<<1, 64, 0, stream>>>(cls, img, out);
  k7_pixel<<<(BIMG * HOUT * WOUT + 255) / 256, 256, 0, stream>>>(scores, out);
}